// Round 1
// baseline (911.241 us; speedup 1.0000x reference)
//
#include <hip/hip_runtime.h>
#include <hip/hip_bf16.h>

using short8 = __attribute__((ext_vector_type(8))) short;
using f32x4  = __attribute__((ext_vector_type(4))) float;

#define K1P 168   // padded K=160 row stride (bf16 elems) for edge MLP layer 1
#define DP  72    // padded 64 row stride for layer 2
#define KLP 136   // padded K=128 row stride for LSTM

__device__ __forceinline__ unsigned short f2bf(float f) {
  unsigned u = __float_as_uint(f);
  u += 0x7FFFu + ((u >> 16) & 1u);
  return (unsigned short)(u >> 16);
}
__device__ __forceinline__ unsigned pack2(float a, float b) {
  return (unsigned)f2bf(a) | ((unsigned)f2bf(b) << 16);
}
__device__ __forceinline__ float sigm(float x) { return 1.f / (1.f + __expf(-x)); }

// ---------------- weight prep: transpose + bf16 cast ----------------
__global__ __launch_bounds__(256) void prep_weights(
    const float* __restrict__ W1_0, const float* __restrict__ W2_0,
    const float* __restrict__ Wih0, const float* __restrict__ Whh0,
    const float* __restrict__ bih0, const float* __restrict__ bhh0,
    const float* __restrict__ W1_1, const float* __restrict__ W2_1,
    const float* __restrict__ Wih1, const float* __restrict__ Whh1,
    const float* __restrict__ bih1, const float* __restrict__ bhh1,
    unsigned short* __restrict__ W1T,  // [2][64*160]  (out-major, k inner)
    unsigned short* __restrict__ W2T,  // [2][64*64]
    unsigned short* __restrict__ WcT,  // [2][256*128]
    float* __restrict__ bG)            // [2][256]
{
  int t = blockIdx.x * 256 + threadIdx.x;
  const int per = 10240 + 4096 + 32768 + 256;  // 47360
  if (t >= 2 * per) return;
  int step = t / per, r = t % per;
  const float* W1  = step ? W1_1 : W1_0;
  const float* W2  = step ? W2_1 : W2_0;
  const float* Wih = step ? Wih1 : Wih0;
  const float* Whh = step ? Whh1 : Whh0;
  const float* bih = step ? bih1 : bih0;
  const float* bhh = step ? bhh1 : bhh0;
  if (r < 10240) {
    int o = r / 160, k = r % 160;
    W1T[step * 10240 + o * 160 + k] = f2bf(W1[k * 64 + o]);
  } else if (r < 14336) {
    int q = r - 10240; int o = q / 64, k = q % 64;
    W2T[step * 4096 + o * 64 + k] = f2bf(W2[k * 64 + o]);
  } else if (r < 47104) {
    int q = r - 14336; int o = q / 128, k = q % 128;
    float v = (k < 64) ? Wih[k * 256 + o] : Whh[(k - 64) * 256 + o];
    WcT[step * 32768 + o * 128 + k] = f2bf(v);
  } else {
    int g = r - 47104;
    bG[step * 256 + g] = bih[g] + bhh[g];
  }
}

__global__ __launch_bounds__(256) void convert_x(
    const float* __restrict__ x, unsigned short* __restrict__ xb, int n)
{
  int i = blockIdx.x * 256 + threadIdx.x;
  if (i < n) xb[i] = f2bf(x[i]);
}

// ---------------- edge MLP + scatter-add ----------------
// per tile of 64 edges: m=[x[dst]|x[src]|ea] (bf16) -> relu(m@W1+b1)@W2+b2 -> atomicAdd a[dst]
__global__ __launch_bounds__(256) void edge_mlp(
    const unsigned short* __restrict__ xb,   // [N][64] bf16
    const float* __restrict__ ea,            // [E][32] f32
    const int* __restrict__ srcI,            // [E]
    const int* __restrict__ dstI,            // [E]
    const unsigned short* __restrict__ W1T,  // [64][160] bf16 (out-major)
    const unsigned short* __restrict__ W2T,  // [64][64]
    const float* __restrict__ b1,
    const float* __restrict__ b2,
    float* __restrict__ aggr,                // [N][64] f32
    int tiles_total)
{
  __shared__ unsigned short sM[64 * K1P];
  __shared__ unsigned short sW1[64 * K1P];
  __shared__ unsigned short sH[64 * DP];
  __shared__ unsigned short sW2[64 * DP];
  __shared__ int   sDst[64];
  __shared__ float sB1[64], sB2[64];
  const int t = threadIdx.x;

  // stage weights once per block
  {
    const uint4* gw1 = (const uint4*)W1T;   // 1280 uint4, 20/row
    uint4* lw1 = (uint4*)sW1;               // 21/row (padded)
    #pragma unroll
    for (int p = 0; p < 5; ++p) {
      int idx = t + p * 256;
      int o = idx / 20, s = idx % 20;
      lw1[o * 21 + s] = gw1[idx];
    }
    const uint4* gw2 = (const uint4*)W2T;   // 512 uint4, 8/row
    uint4* lw2 = (uint4*)sW2;               // 9/row
    #pragma unroll
    for (int p = 0; p < 2; ++p) {
      int idx = t + p * 256;
      int o = idx / 8, s = idx % 8;
      lw2[o * 9 + s] = gw2[idx];
    }
    if (t < 64) { sB1[t] = b1[t]; sB2[t] = b2[t]; }
  }

  const int w = t >> 6, l = t & 63, quad = l >> 4, lr = l & 15;
  const int row0 = w * 16;
  const int el = t >> 2, q = t & 3;

  for (int tile = blockIdx.x; tile < tiles_total; tile += gridDim.x) {
    long long e = (long long)tile * 64 + el;
    int s_n = srcI[e];
    int d_n = dstI[e];
    if (q == 0) sDst[el] = d_n;
    uint4* pm = (uint4*)sM + el * 21;
    const uint4* pd = (const uint4*)xb + (long long)d_n * 8;
    const uint4* ps = (const uint4*)xb + (long long)s_n * 8;
    pm[q]      = pd[q];
    pm[q + 4]  = pd[q + 4];
    pm[8 + q]  = ps[q];
    pm[12 + q] = ps[q + 4];
    const float4* pe = (const float4*)ea + e * 8;
    float4 f0 = pe[q * 2], f1 = pe[q * 2 + 1];
    pm[16 + q] = make_uint4(pack2(f0.x, f0.y), pack2(f0.z, f0.w),
                            pack2(f1.x, f1.y), pack2(f1.z, f1.w));
    __syncthreads();

    // GEMM1: h1[64x64] = relu(m[64x160] @ W1 + b1)
    f32x4 acc[4] = {};
    #pragma unroll
    for (int kc = 0; kc < 5; ++kc) {
      short8 aF = *(const short8*)(sM + (row0 + lr) * K1P + kc * 32 + quad * 8);
      #pragma unroll
      for (int n = 0; n < 4; ++n) {
        short8 bF = *(const short8*)(sW1 + (n * 16 + lr) * K1P + kc * 32 + quad * 8);
        acc[n] = __builtin_amdgcn_mfma_f32_16x16x32_bf16(aF, bF, acc[n], 0, 0, 0);
      }
    }
    #pragma unroll
    for (int n = 0; n < 4; ++n) {
      int col = n * 16 + lr;
      float bb = sB1[col];
      #pragma unroll
      for (int r = 0; r < 4; ++r) {
        int er = row0 + quad * 4 + r;
        float v = acc[n][r] + bb;
        v = v > 0.f ? v : 0.f;
        sH[er * DP + col] = f2bf(v);
      }
    }
    __syncthreads();

    // GEMM2: out[64x64] = h1 @ W2 + b2 ; scatter
    f32x4 acc2[4] = {};
    #pragma unroll
    for (int kc = 0; kc < 2; ++kc) {
      short8 aF = *(const short8*)(sH + (row0 + lr) * DP + kc * 32 + quad * 8);
      #pragma unroll
      for (int n = 0; n < 4; ++n) {
        short8 bF = *(const short8*)(sW2 + (n * 16 + lr) * DP + kc * 32 + quad * 8);
        acc2[n] = __builtin_amdgcn_mfma_f32_16x16x32_bf16(aF, bF, acc2[n], 0, 0, 0);
      }
    }
    #pragma unroll
    for (int n = 0; n < 4; ++n) {
      int col = n * 16 + lr;
      float bb = sB2[col];
      #pragma unroll
      for (int r = 0; r < 4; ++r) {
        int er = row0 + quad * 4 + r;
        float v = acc2[n][r] + bb;
        unsafeAtomicAdd(&aggr[(long long)sDst[er] * 64 + col], v);
      }
    }
    __syncthreads();
  }
}

// ---------------- LSTM cell ----------------
// gates[64n x 256] = concat(x,a)[64 x 128] @ WcatT^T ; then elementwise update
__global__ __launch_bounds__(256) void lstm_kernel(
    const float* __restrict__ xin,
    const float* __restrict__ ain,
    float* __restrict__ cbuf,
    const unsigned short* __restrict__ WcT,  // [256][128] bf16 (out-major)
    const float* __restrict__ bG,            // [256] = bih+bhh
    float* __restrict__ xout,
    unsigned short* __restrict__ xbf_out,    // may be null
    int nNodes)
{
  __shared__ unsigned short sIn[64 * KLP];
  __shared__ unsigned short sW[64 * KLP];
  __shared__ float sBG[256];
  const int t = threadIdx.x;
  sBG[t] = bG[t];
  const int base = blockIdx.x * 64;
  const int nl = t >> 2, q = t & 3;
  const int node = base + nl;
  if (node < nNodes) {
    const float4* px = (const float4*)(xin + (long long)node * 64);
    const float4* pa = (const float4*)(ain + (long long)node * 64);
    #pragma unroll
    for (int j = 0; j < 4; ++j) {
      int jj = q * 4 + j;
      float4 v = px[jj];
      *(uint2*)(sIn + nl * KLP + jj * 4) = make_uint2(pack2(v.x, v.y), pack2(v.z, v.w));
      float4 u = pa[jj];
      *(uint2*)(sIn + nl * KLP + 64 + jj * 4) = make_uint2(pack2(u.x, u.y), pack2(u.z, u.w));
    }
  } else {
    #pragma unroll
    for (int j = 0; j < 4; ++j) {
      int jj = q * 4 + j;
      *(uint2*)(sIn + nl * KLP + jj * 4) = make_uint2(0, 0);
      *(uint2*)(sIn + nl * KLP + 64 + jj * 4) = make_uint2(0, 0);
    }
  }

  const int w = t >> 6, l = t & 63, quad = l >> 4, lr = l & 15;
  const int row0 = w * 16;
  f32x4 acc[16] = {};
  for (int grp = 0; grp < 4; ++grp) {
    // stage 64 gate-output rows of WcT
    const uint4* gw = (const uint4*)WcT + (long long)(grp * 64) * 16;  // 16 uint4/row
    uint4* lw = (uint4*)sW;                                            // 17/row padded
    {
      int o0 = t >> 4, s = t & 15;
      #pragma unroll
      for (int p = 0; p < 4; ++p) {
        int o = p * 16 + o0;
        lw[o * 17 + s] = gw[o * 16 + s];
      }
    }
    __syncthreads();
    #pragma unroll
    for (int kc = 0; kc < 4; ++kc) {
      short8 aF = *(const short8*)(sIn + (row0 + lr) * KLP + kc * 32 + quad * 8);
      #pragma unroll
      for (int nt = 0; nt < 4; ++nt) {
        short8 bF = *(const short8*)(sW + (nt * 16 + lr) * KLP + kc * 32 + quad * 8);
        acc[grp * 4 + nt] = __builtin_amdgcn_mfma_f32_16x16x32_bf16(aF, bF, acc[grp * 4 + nt], 0, 0, 0);
      }
    }
    __syncthreads();
  }

  // elementwise LSTM update; gate i=grp0, f=grp1, g=grp2, o=grp3
  #pragma unroll
  for (int nt = 0; nt < 4; ++nt) {
    #pragma unroll
    for (int r = 0; r < 4; ++r) {
      int node2 = base + row0 + quad * 4 + r;
      if (node2 < nNodes) {
        int col = nt * 16 + lr;
        long long off = (long long)node2 * 64 + col;
        float iv = acc[nt][r]      + sBG[col];
        float fv = acc[4 + nt][r]  + sBG[64 + col];
        float gv = acc[8 + nt][r]  + sBG[128 + col];
        float ov = acc[12 + nt][r] + sBG[192 + col];
        float cOld = cbuf[off];
        float cN = sigm(fv) * cOld + sigm(iv) * tanhf(gv);
        float hN = sigm(ov) * tanhf(cN);
        cbuf[off] = cN;
        xout[off] = hN;
        if (xbf_out) xbf_out[off] = f2bf(hN);
      }
    }
  }
}

// ---------------- readout: out[g] = sum_n sigmoid(x@gW+gb) * (x@fW+fb) ----------------
__global__ __launch_bounds__(256) void readout(
    const float* __restrict__ x,
    const float* __restrict__ gW, const float* __restrict__ gb,
    const float* __restrict__ fW, const float* __restrict__ fb,
    float* __restrict__ out, int nNodes)
{
  __shared__ float sG[64 * 50], sF[64 * 50], sGb[50], sFb[50];
  const int t = threadIdx.x;
  for (int i = t; i < 64 * 50; i += 256) { sG[i] = gW[i]; sF[i] = fW[i]; }
  if (t < 50) { sGb[t] = gb[t]; sFb[t] = fb[t]; }
  __syncthreads();
  const int node = blockIdx.x * 256 + t;
  const bool valid = node < nNodes;
  float xr[64];
  if (valid) {
    const float4* px = (const float4*)(x + (long long)node * 64);
    #pragma unroll
    for (int j = 0; j < 16; ++j) {
      float4 v = px[j];
      xr[4*j] = v.x; xr[4*j+1] = v.y; xr[4*j+2] = v.z; xr[4*j+3] = v.w;
    }
  } else {
    #pragma unroll
    for (int j = 0; j < 64; ++j) xr[j] = 0.f;
  }
  const int lane = t & 63;
  for (int g = 0; g < 50; ++g) {
    float dg = 0.f, df = 0.f;
    #pragma unroll
    for (int k = 0; k < 64; ++k) {
      dg = fmaf(xr[k], sG[k * 50 + g], dg);
      df = fmaf(xr[k], sF[k * 50 + g], df);
    }
    float val = valid ? sigm(dg + sGb[g]) * (df + sFb[g]) : 0.f;
    #pragma unroll
    for (int off = 32; off; off >>= 1) val += __shfl_down(val, off);
    if (lane == 0) unsafeAtomicAdd(&out[g], val);
  }
}

extern "C" void kernel_launch(void* const* d_in, const int* in_sizes, int n_in,
                              void* d_out, int out_size, void* d_ws, size_t ws_size,
                              hipStream_t stream)
{
  const float* x      = (const float*)d_in[0];
  const float* ea     = (const float*)d_in[1];
  const int*   ei     = (const int*)d_in[2];   // int32 per harness convention
  const float* fe0_W1 = (const float*)d_in[3];
  const float* fe0_b1 = (const float*)d_in[4];
  const float* fe0_W2 = (const float*)d_in[5];
  const float* fe0_b2 = (const float*)d_in[6];
  const float* l0_Wih = (const float*)d_in[7];
  const float* l0_Whh = (const float*)d_in[8];
  const float* l0_bih = (const float*)d_in[9];
  const float* l0_bhh = (const float*)d_in[10];
  const float* fe1_W1 = (const float*)d_in[11];
  const float* fe1_b1 = (const float*)d_in[12];
  const float* fe1_W2 = (const float*)d_in[13];
  const float* fe1_b2 = (const float*)d_in[14];
  const float* l1_Wih = (const float*)d_in[15];
  const float* l1_Whh = (const float*)d_in[16];
  const float* l1_bih = (const float*)d_in[17];
  const float* l1_bhh = (const float*)d_in[18];
  const float* gm_W   = (const float*)d_in[19];
  const float* gm_b   = (const float*)d_in[20];
  const float* fm_W   = (const float*)d_in[21];
  const float* fm_b   = (const float*)d_in[22];

  const int N = in_sizes[0] / 64;    // 50000
  const int E = in_sizes[1] / 32;    // 800000
  const int* srcI = ei;
  const int* dstI = ei + E;

  char* ws = (char*)d_ws;
  unsigned short* xb  = (unsigned short*)ws;               // N*64*2  = 6.4 MB
  float* x1   = (float*)(ws + 6400000);                    // 12.8 MB
  float* aggr = (float*)(ws + 19200000);                   // 12.8 MB
  float* cbuf = (float*)(ws + 32000000);                   // 12.8 MB
  unsigned short* W1T = (unsigned short*)(ws + 44800000);  // 2*20480 B
  unsigned short* W2T = (unsigned short*)(ws + 44840960);  // 2*8192 B
  unsigned short* WcT = (unsigned short*)(ws + 44857344);  // 2*65536 B
  float* bG = (float*)(ws + 44988416);                     // 2*1024 B

  hipMemsetAsync(d_out, 0, out_size * sizeof(float), stream);
  hipMemsetAsync(cbuf, 0, (size_t)N * 64 * 4, stream);
  hipMemsetAsync(aggr, 0, (size_t)N * 64 * 4, stream);

  prep_weights<<<(2 * 47360 + 255) / 256, 256, 0, stream>>>(
      fe0_W1, fe0_W2, l0_Wih, l0_Whh, l0_bih, l0_bhh,
      fe1_W1, fe1_W2, l1_Wih, l1_Whh, l1_bih, l1_bhh,
      W1T, W2T, WcT, bG);
  convert_x<<<(N * 64 + 255) / 256, 256, 0, stream>>>(x, xb, N * 64);

  // step 0
  edge_mlp<<<1024, 256, 0, stream>>>(xb, ea, srcI, dstI, W1T, W2T,
                                     fe0_b1, fe0_b2, aggr, E / 64);
  lstm_kernel<<<(N + 63) / 64, 256, 0, stream>>>(x, aggr, cbuf, WcT, bG, x1, xb, N);

  // step 1
  hipMemsetAsync(aggr, 0, (size_t)N * 64 * 4, stream);
  edge_mlp<<<1024, 256, 0, stream>>>(xb, ea, srcI, dstI, W1T + 10240, W2T + 4096,
                                     fe1_b1, fe1_b2, aggr, E / 64);
  lstm_kernel<<<(N + 63) / 64, 256, 0, stream>>>(x1, aggr, cbuf, WcT + 32768, bG + 256,
                                                 x1, nullptr, N);

  readout<<<(N + 255) / 256, 256, 0, stream>>>(x1, gm_W, gm_b, fm_W, fm_b,
                                               (float*)d_out, N);
}

// Round 2
// 612.705 us; speedup vs baseline: 1.4872x; 1.4872x over previous
//
#include <hip/hip_runtime.h>
#include <hip/hip_bf16.h>

using short8 = __attribute__((ext_vector_type(8))) short;
using f32x4  = __attribute__((ext_vector_type(4))) float;

#define K1P 168   // padded K=160 row stride (bf16 elems) for edge MLP layer 1
#define DP  72    // padded 64 row stride for layer 2
#define KLP 136   // padded K=128 row stride for LSTM

__device__ __forceinline__ unsigned short f2bf(float f) {
  unsigned u = __float_as_uint(f);
  u += 0x7FFFu + ((u >> 16) & 1u);
  return (unsigned short)(u >> 16);
}
__device__ __forceinline__ unsigned pack2(float a, float b) {
  return (unsigned)f2bf(a) | ((unsigned)f2bf(b) << 16);
}
__device__ __forceinline__ float sigm(float x) { return 1.f / (1.f + __expf(-x)); }

// ---------------- weight prep: transpose + bf16 cast ----------------
__global__ __launch_bounds__(256) void prep_weights(
    const float* __restrict__ W1_0, const float* __restrict__ W2_0,
    const float* __restrict__ Wih0, const float* __restrict__ Whh0,
    const float* __restrict__ bih0, const float* __restrict__ bhh0,
    const float* __restrict__ W1_1, const float* __restrict__ W2_1,
    const float* __restrict__ Wih1, const float* __restrict__ Whh1,
    const float* __restrict__ bih1, const float* __restrict__ bhh1,
    const float* __restrict__ gmW, const float* __restrict__ fmW,
    unsigned short* __restrict__ W1T,  // [2][64*160]  (out-major, k inner)
    unsigned short* __restrict__ W2T,  // [2][64*64]
    unsigned short* __restrict__ WcT,  // [2][256*128]
    float* __restrict__ bG,            // [2][256]
    unsigned short* __restrict__ WrT)  // [128][64] readout: cols 0..49 gW, 64..113 fW
{
  int t = blockIdx.x * 256 + threadIdx.x;
  const int per = 10240 + 4096 + 32768 + 256;  // 47360
  if (t >= 2 * per + 8192) return;
  if (t >= 2 * per) {
    int r2 = t - 2 * per;
    int o = r2 >> 6, k = r2 & 63;
    float v = 0.f;
    if (o < 50) v = gmW[k * 50 + o];
    else if (o >= 64 && o < 114) v = fmW[k * 50 + (o - 64)];
    WrT[o * 64 + k] = f2bf(v);
    return;
  }
  int step = t / per, r = t % per;
  const float* W1  = step ? W1_1 : W1_0;
  const float* W2  = step ? W2_1 : W2_0;
  const float* Wih = step ? Wih1 : Wih0;
  const float* Whh = step ? Whh1 : Whh0;
  const float* bih = step ? bih1 : bih0;
  const float* bhh = step ? bhh1 : bhh0;
  if (r < 10240) {
    int o = r / 160, k = r % 160;
    W1T[step * 10240 + o * 160 + k] = f2bf(W1[k * 64 + o]);
  } else if (r < 14336) {
    int q = r - 10240; int o = q / 64, k = q % 64;
    W2T[step * 4096 + o * 64 + k] = f2bf(W2[k * 64 + o]);
  } else if (r < 47104) {
    int q = r - 14336; int o = q / 128, k = q % 128;
    float v = (k < 64) ? Wih[k * 256 + o] : Whh[(k - 64) * 256 + o];
    WcT[step * 32768 + o * 128 + k] = f2bf(v);
  } else {
    int g = r - 47104;
    bG[step * 256 + g] = bih[g] + bhh[g];
  }
}

__global__ __launch_bounds__(256) void convert_x(
    const float* __restrict__ x, unsigned short* __restrict__ xb, int n)
{
  int i = blockIdx.x * 256 + threadIdx.x;
  if (i < n) xb[i] = f2bf(x[i]);
}

// ---------------- edge MLP + scatter-add ----------------
__global__ __launch_bounds__(256) void edge_mlp(
    const unsigned short* __restrict__ xb,   // [N][64] bf16
    const float* __restrict__ ea,            // [E][32] f32
    const int* __restrict__ srcI,            // [E]
    const int* __restrict__ dstI,            // [E]
    const unsigned short* __restrict__ W1T,  // [64][160] bf16 (out-major)
    const unsigned short* __restrict__ W2T,  // [64][64]
    const float* __restrict__ b1,
    const float* __restrict__ b2,
    float* __restrict__ aggr,                // [N][64] f32
    int tiles_total)
{
  __shared__ unsigned short sM[64 * K1P];
  __shared__ unsigned short sW1[64 * K1P];
  __shared__ unsigned short sH[64 * DP];
  __shared__ unsigned short sW2[64 * DP];
  __shared__ int   sDst[64];
  __shared__ float sB1[64], sB2[64];
  const int t = threadIdx.x;

  // stage weights once per block
  {
    const uint4* gw1 = (const uint4*)W1T;   // 1280 uint4, 20/row
    uint4* lw1 = (uint4*)sW1;               // 21/row (padded)
    #pragma unroll
    for (int p = 0; p < 5; ++p) {
      int idx = t + p * 256;
      int o = idx / 20, s = idx % 20;
      lw1[o * 21 + s] = gw1[idx];
    }
    const uint4* gw2 = (const uint4*)W2T;   // 512 uint4, 8/row
    uint4* lw2 = (uint4*)sW2;               // 9/row
    #pragma unroll
    for (int p = 0; p < 2; ++p) {
      int idx = t + p * 256;
      int o = idx / 8, s = idx % 8;
      lw2[o * 9 + s] = gw2[idx];
    }
    if (t < 64) { sB1[t] = b1[t]; sB2[t] = b2[t]; }
  }

  const int w = t >> 6, l = t & 63, quad = l >> 4, lr = l & 15;
  const int row0 = w * 16;
  const int el = t >> 2, q = t & 3;

  for (int tile = blockIdx.x; tile < tiles_total; tile += gridDim.x) {
    long long e = (long long)tile * 64 + el;
    int s_n = srcI[e];
    int d_n = dstI[e];
    if (q == 0) sDst[el] = d_n;
    uint4* pm = (uint4*)sM + el * 21;
    const uint4* pd = (const uint4*)xb + (long long)d_n * 8;
    const uint4* ps = (const uint4*)xb + (long long)s_n * 8;
    pm[q]      = pd[q];
    pm[q + 4]  = pd[q + 4];
    pm[8 + q]  = ps[q];
    pm[12 + q] = ps[q + 4];
    const float4* pe = (const float4*)ea + e * 8;
    float4 f0 = pe[q * 2], f1 = pe[q * 2 + 1];
    pm[16 + q] = make_uint4(pack2(f0.x, f0.y), pack2(f0.z, f0.w),
                            pack2(f1.x, f1.y), pack2(f1.z, f1.w));
    __syncthreads();

    // GEMM1: h1[64x64] = relu(m[64x160] @ W1 + b1)
    f32x4 acc[4] = {};
    #pragma unroll
    for (int kc = 0; kc < 5; ++kc) {
      short8 aF = *(const short8*)(sM + (row0 + lr) * K1P + kc * 32 + quad * 8);
      #pragma unroll
      for (int n = 0; n < 4; ++n) {
        short8 bF = *(const short8*)(sW1 + (n * 16 + lr) * K1P + kc * 32 + quad * 8);
        acc[n] = __builtin_amdgcn_mfma_f32_16x16x32_bf16(aF, bF, acc[n], 0, 0, 0);
      }
    }
    #pragma unroll
    for (int n = 0; n < 4; ++n) {
      int col = n * 16 + lr;
      float bb = sB1[col];
      #pragma unroll
      for (int r = 0; r < 4; ++r) {
        int er = row0 + quad * 4 + r;
        float v = acc[n][r] + bb;
        v = v > 0.f ? v : 0.f;
        sH[er * DP + col] = f2bf(v);
      }
    }
    __syncthreads();

    // GEMM2: out[64x64] = h1 @ W2 + b2 ; scatter
    f32x4 acc2[4] = {};
    #pragma unroll
    for (int kc = 0; kc < 2; ++kc) {
      short8 aF = *(const short8*)(sH + (row0 + lr) * DP + kc * 32 + quad * 8);
      #pragma unroll
      for (int n = 0; n < 4; ++n) {
        short8 bF = *(const short8*)(sW2 + (n * 16 + lr) * DP + kc * 32 + quad * 8);
        acc2[n] = __builtin_amdgcn_mfma_f32_16x16x32_bf16(aF, bF, acc2[n], 0, 0, 0);
      }
    }
    #pragma unroll
    for (int n = 0; n < 4; ++n) {
      int col = n * 16 + lr;
      float bb = sB2[col];
      #pragma unroll
      for (int r = 0; r < 4; ++r) {
        int er = row0 + quad * 4 + r;
        float v = acc2[n][r] + bb;
        unsafeAtomicAdd(&aggr[(long long)sDst[er] * 64 + col], v);
      }
    }
    __syncthreads();
  }
}

// ---------------- LSTM cell ----------------
__global__ __launch_bounds__(256) void lstm_kernel(
    const float* __restrict__ xin,
    const float* __restrict__ ain,
    float* __restrict__ cbuf,
    const unsigned short* __restrict__ WcT,  // [256][128] bf16 (out-major)
    const float* __restrict__ bG,            // [256] = bih+bhh
    float* __restrict__ xout,
    unsigned short* __restrict__ xbf_out,    // may be null
    int nNodes)
{
  __shared__ unsigned short sIn[64 * KLP];
  __shared__ unsigned short sW[64 * KLP];
  __shared__ float sBG[256];
  const int t = threadIdx.x;
  sBG[t] = bG[t];
  const int base = blockIdx.x * 64;
  const int nl = t >> 2, q = t & 3;
  const int node = base + nl;
  if (node < nNodes) {
    const float4* px = (const float4*)(xin + (long long)node * 64);
    const float4* pa = (const float4*)(ain + (long long)node * 64);
    #pragma unroll
    for (int j = 0; j < 4; ++j) {
      int jj = q * 4 + j;
      float4 v = px[jj];
      *(uint2*)(sIn + nl * KLP + jj * 4) = make_uint2(pack2(v.x, v.y), pack2(v.z, v.w));
      float4 u = pa[jj];
      *(uint2*)(sIn + nl * KLP + 64 + jj * 4) = make_uint2(pack2(u.x, u.y), pack2(u.z, u.w));
    }
  } else {
    #pragma unroll
    for (int j = 0; j < 4; ++j) {
      int jj = q * 4 + j;
      *(uint2*)(sIn + nl * KLP + jj * 4) = make_uint2(0, 0);
      *(uint2*)(sIn + nl * KLP + 64 + jj * 4) = make_uint2(0, 0);
    }
  }

  const int w = t >> 6, l = t & 63, quad = l >> 4, lr = l & 15;
  const int row0 = w * 16;
  f32x4 acc[16] = {};
  for (int grp = 0; grp < 4; ++grp) {
    const uint4* gw = (const uint4*)WcT + (long long)(grp * 64) * 16;  // 16 uint4/row
    uint4* lw = (uint4*)sW;                                            // 17/row padded
    {
      int o0 = t >> 4, s = t & 15;
      #pragma unroll
      for (int p = 0; p < 4; ++p) {
        int o = p * 16 + o0;
        lw[o * 17 + s] = gw[o * 16 + s];
      }
    }
    __syncthreads();
    #pragma unroll
    for (int kc = 0; kc < 4; ++kc) {
      short8 aF = *(const short8*)(sIn + (row0 + lr) * KLP + kc * 32 + quad * 8);
      #pragma unroll
      for (int nt = 0; nt < 4; ++nt) {
        short8 bF = *(const short8*)(sW + (nt * 16 + lr) * KLP + kc * 32 + quad * 8);
        acc[grp * 4 + nt] = __builtin_amdgcn_mfma_f32_16x16x32_bf16(aF, bF, acc[grp * 4 + nt], 0, 0, 0);
      }
    }
    __syncthreads();
  }

  #pragma unroll
  for (int nt = 0; nt < 4; ++nt) {
    #pragma unroll
    for (int r = 0; r < 4; ++r) {
      int node2 = base + row0 + quad * 4 + r;
      if (node2 < nNodes) {
        int col = nt * 16 + lr;
        long long off = (long long)node2 * 64 + col;
        float iv = acc[nt][r]      + sBG[col];
        float fv = acc[4 + nt][r]  + sBG[64 + col];
        float gv = acc[8 + nt][r]  + sBG[128 + col];
        float ov = acc[12 + nt][r] + sBG[192 + col];
        float cOld = cbuf[off];
        float cN = sigm(fv) * cOld + sigm(iv) * tanhf(gv);
        float hN = sigm(ov) * tanhf(cN);
        cbuf[off] = cN;
        xout[off] = hN;
        if (xbf_out) xbf_out[off] = f2bf(hN);
      }
    }
  }
}

// ---------------- readout v2 (MFMA): out[g] = sum_n sigm(x@gW+gb)*(x@fW+fb) ----------------
// WrT[128][64] bf16 out-major: cols 0..49 = gW^T, 64..113 = fW^T, rest 0.
__global__ __launch_bounds__(256) void readout(
    const float* __restrict__ x,
    const unsigned short* __restrict__ WrT,
    const float* __restrict__ gb, const float* __restrict__ fb,
    float* __restrict__ out, int nNodes)
{
  __shared__ unsigned short sX[64 * 72];
  __shared__ unsigned short sW[128 * 72];
  __shared__ float sOut[4][64];
  __shared__ float sGb[64], sFb[64];
  const int t = threadIdx.x;

  // stage weights: 128 rows x 8 uint4
  {
    const uint4* gw = (const uint4*)WrT;  // 1024 uint4
    uint4* lw = (uint4*)sW;               // 9 uint4/row (padded)
    #pragma unroll
    for (int p = 0; p < 4; ++p) {
      int idx = t + p * 256;
      int o = idx >> 3, s = idx & 7;
      lw[o * 9 + s] = gw[idx];
    }
    if (t < 50)      { sGb[t] = gb[t]; sFb[t] = fb[t]; }
    else if (t < 64) { sGb[t] = 0.f;   sFb[t] = 0.f; }
  }

  const int base = blockIdx.x * 64;
  const int nl = t >> 2, q = t & 3;
  const int node = base + nl;
  {
    uint2* dst = (uint2*)(sX + nl * 72 + q * 16);
    if (node < nNodes) {
      const float4* px = (const float4*)(x + (long long)node * 64) + q * 4;
      #pragma unroll
      for (int j = 0; j < 4; ++j) {
        float4 v = px[j];
        dst[j] = make_uint2(pack2(v.x, v.y), pack2(v.z, v.w));
      }
    } else {
      #pragma unroll
      for (int j = 0; j < 4; ++j) dst[j] = make_uint2(0, 0);
    }
  }
  __syncthreads();

  const int w = t >> 6, l = t & 63, quad = l >> 4, lr = l & 15;
  f32x4 acc[8] = {};
  #pragma unroll
  for (int kc = 0; kc < 2; ++kc) {
    short8 aF = *(const short8*)(sX + (w * 16 + lr) * 72 + kc * 32 + quad * 8);
    #pragma unroll
    for (int n = 0; n < 8; ++n) {
      short8 bF = *(const short8*)(sW + (n * 16 + lr) * 72 + kc * 32 + quad * 8);
      acc[n] = __builtin_amdgcn_mfma_f32_16x16x32_bf16(aF, bF, acc[n], 0, 0, 0);
    }
  }

  // epilogue: column j=n*16+lr (n<4): g from acc[n], f from acc[n+4]; same lane, same reg.
  #pragma unroll
  for (int n = 0; n < 4; ++n) {
    float val = 0.f;
    #pragma unroll
    for (int r = 0; r < 4; ++r) {
      int nd = base + w * 16 + quad * 4 + r;
      if (nd < nNodes) {
        int jj = n * 16 + lr;
        float gv = sigm(acc[n][r] + sGb[jj]);
        float fv = acc[n + 4][r] + sFb[jj];
        val += gv * fv;
      }
    }
    // reduce over quad (rows): lanes same lr, quad 0..3
    val += __shfl_xor(val, 16);
    val += __shfl_xor(val, 32);
    if (quad == 0) sOut[w][n * 16 + lr] = val;
  }
  __syncthreads();
  if (t < 50) {
    float s = sOut[0][t] + sOut[1][t] + sOut[2][t] + sOut[3][t];
    unsafeAtomicAdd(&out[t], s);
  }
}

extern "C" void kernel_launch(void* const* d_in, const int* in_sizes, int n_in,
                              void* d_out, int out_size, void* d_ws, size_t ws_size,
                              hipStream_t stream)
{
  const float* x      = (const float*)d_in[0];
  const float* ea     = (const float*)d_in[1];
  const int*   ei     = (const int*)d_in[2];
  const float* fe0_W1 = (const float*)d_in[3];
  const float* fe0_b1 = (const float*)d_in[4];
  const float* fe0_W2 = (const float*)d_in[5];
  const float* fe0_b2 = (const float*)d_in[6];
  const float* l0_Wih = (const float*)d_in[7];
  const float* l0_Whh = (const float*)d_in[8];
  const float* l0_bih = (const float*)d_in[9];
  const float* l0_bhh = (const float*)d_in[10];
  const float* fe1_W1 = (const float*)d_in[11];
  const float* fe1_b1 = (const float*)d_in[12];
  const float* fe1_W2 = (const float*)d_in[13];
  const float* fe1_b2 = (const float*)d_in[14];
  const float* l1_Wih = (const float*)d_in[15];
  const float* l1_Whh = (const float*)d_in[16];
  const float* l1_bih = (const float*)d_in[17];
  const float* l1_bhh = (const float*)d_in[18];
  const float* gm_W   = (const float*)d_in[19];
  const float* gm_b   = (const float*)d_in[20];
  const float* fm_W   = (const float*)d_in[21];
  const float* fm_b   = (const float*)d_in[22];

  const int N = in_sizes[0] / 64;    // 50000
  const int E = in_sizes[1] / 32;    // 800000
  const int* srcI = ei;
  const int* dstI = ei + E;

  char* ws = (char*)d_ws;
  unsigned short* xb  = (unsigned short*)ws;               // N*64*2  = 6.4 MB
  float* x1   = (float*)(ws + 6400000);                    // 12.8 MB
  float* aggr = (float*)(ws + 19200000);                   // 12.8 MB
  float* cbuf = (float*)(ws + 32000000);                   // 12.8 MB
  unsigned short* W1T = (unsigned short*)(ws + 44800000);  // 2*20480 B
  unsigned short* W2T = (unsigned short*)(ws + 44840960);  // 2*8192 B
  unsigned short* WcT = (unsigned short*)(ws + 44857344);  // 2*65536 B
  float* bG = (float*)(ws + 44988416);                     // 2*1024 B
  unsigned short* WrT = (unsigned short*)(ws + 44990464);  // 16384 B

  hipMemsetAsync(d_out, 0, out_size * sizeof(float), stream);
  hipMemsetAsync(cbuf, 0, (size_t)N * 64 * 4, stream);
  hipMemsetAsync(aggr, 0, (size_t)N * 64 * 4, stream);

  prep_weights<<<(2 * 47360 + 8192 + 255) / 256, 256, 0, stream>>>(
      fe0_W1, fe0_W2, l0_Wih, l0_Whh, l0_bih, l0_bhh,
      fe1_W1, fe1_W2, l1_Wih, l1_Whh, l1_bih, l1_bhh,
      gm_W, fm_W, W1T, W2T, WcT, bG, WrT);
  convert_x<<<(N * 64 + 255) / 256, 256, 0, stream>>>(x, xb, N * 64);

  // step 0
  edge_mlp<<<1024, 256, 0, stream>>>(xb, ea, srcI, dstI, W1T, W2T,
                                     fe0_b1, fe0_b2, aggr, E / 64);
  lstm_kernel<<<(N + 63) / 64, 256, 0, stream>>>(x, aggr, cbuf, WcT, bG, x1, xb, N);

  // step 1
  hipMemsetAsync(aggr, 0, (size_t)N * 64 * 4, stream);
  edge_mlp<<<1024, 256, 0, stream>>>(xb, ea, srcI, dstI, W1T + 10240, W2T + 4096,
                                     fe1_b1, fe1_b2, aggr, E / 64);
  lstm_kernel<<<(N + 63) / 64, 256, 0, stream>>>(x1, aggr, cbuf, WcT + 32768, bG + 256,
                                                 x1, nullptr, N);

  readout<<<(N + 63) / 64, 256, 0, stream>>>(x1, WrT, gm_b, fm_b, (float*)d_out, N);
}